// Round 3
// baseline (884.933 us; speedup 1.0000x reference)
//
#include <hip/hip_runtime.h>

#define HH 4096
#define BB 4096
#define IND 1024
#define NTOT 16777216   // 4096*4096
#define EPSV 1e-5f

typedef unsigned short u16;
typedef __bf16 bf16x8 __attribute__((ext_vector_type(8)));
typedef float f32x4 __attribute__((ext_vector_type(4)));
typedef u16 u16x8 __attribute__((ext_vector_type(8)));

__device__ __forceinline__ u16 f2bf(float f) {
    unsigned u = __builtin_bit_cast(unsigned, f);
    u += 0x7fffu + ((u >> 16) & 1u);
    return (u16)(u >> 16);
}
__device__ __forceinline__ float bf2f(u16 h) {
    return __builtin_bit_cast(float, ((unsigned)h) << 16);
}

// ---------------- f32 -> bf16 conversion ----------------
__global__ void cvt_kernel(const float* __restrict__ src, u16* __restrict__ dst, int n) {
    int i4 = (blockIdx.x * blockDim.x + threadIdx.x) * 4;
    int stride = gridDim.x * blockDim.x * 4;
    for (; i4 < n; i4 += stride) {
        f32x4 v = *(const f32x4*)(src + i4);
        u16 o0 = f2bf(v[0]), o1 = f2bf(v[1]), o2 = f2bf(v[2]), o3 = f2bf(v[3]);
        unsigned p0 = (unsigned)o0 | ((unsigned)o1 << 16);
        unsigned p1 = (unsigned)o2 | ((unsigned)o3 << 16);
        *(uint2*)(dst + i4) = make_uint2(p0, p1);
    }
}

// ---------------- fused GRU GEMM (R1 structure + st_16x32 LDS swizzle) ----
// 128x128 tile, BK=64, 4 waves. LDS tile layout: 16 subtiles of 16rows x 32cols
// (1024B each); within subtile, element (r,c) at byte ((r&15)*64 | (c&31)*2)
// ^ ((r&8)<<2). Staged via inverse-swizzled GLOBAL source with linear
// global_load_lds dest (both-sides-or-neither, G21). Kills the 16-way
// bank conflict of the linear [128][64] layout (R1: 1.9e8 conflicts).

__device__ __forceinline__ void stage_tile(const u16* __restrict__ g, int ld, int row0, int k0,
                                           u16* lds, int tid) {
    const int l = tid & 63, w = tid >> 6;
#pragma unroll
    for (int j = 0; j < 4; ++j) {
        const int sub = j * 4 + w;                  // 0..15, wave-uniform
        const int d = l << 4;                       // linear byte chunk in subtile
        const int lin = d ^ (((d >> 9) & 1) << 5);  // involution: source element
        const int r = ((sub >> 1) << 4) | (lin >> 6);
        const int c = ((sub & 1) << 5) | ((lin & 63) >> 1);
        const u16* ga = g + (size_t)(row0 + r) * ld + (k0 + c);
        __builtin_amdgcn_global_load_lds(
            (const __attribute__((address_space(1))) unsigned*)ga,
            (__attribute__((address_space(3))) unsigned*)(lds + (sub << 9)),
            16, 0, 0);
    }
}

__device__ __forceinline__ void zero_acc(f32x4 (&acc)[4][4]) {
#pragma unroll
    for (int i = 0; i < 4; ++i)
#pragma unroll
        for (int j = 0; j < 4; ++j) {
            f32x4 zz = {0.f, 0.f, 0.f, 0.f};
            acc[i][j] = zz;
        }
}

__device__ __forceinline__ void run_phase(const u16* __restrict__ A, int row0a,
                                          const u16* __restrict__ B, int ld, int Klen,
                                          u16* Alds, u16* Blds,
                                          f32x4 (&acc)[4][4], int tid) {
    const int l = tid & 63;
    const int wid = tid >> 6;
    const int wr = wid >> 1, wc = wid & 1;
    const int lr = l & 15, lq = l >> 4;
    // lane-invariant swizzled offset within a subtile (u16 units)
    const int swzh = (((lr << 6) | (lq << 4)) ^ ((lr & 8) << 2)) >> 1;
    for (int k0 = 0; k0 < Klen; k0 += 64) {
        stage_tile(A, ld, row0a, k0, Alds, tid);
        stage_tile(B, ld, 0, k0, Blds, tid);
        __syncthreads();
#pragma unroll
        for (int kk = 0; kk < 2; ++kk) {
            bf16x8 af[4], bfr[4];
#pragma unroll
            for (int i = 0; i < 4; ++i)
                af[i] = *(const bf16x8*)(Alds + ((wr * 8 + i * 2 + kk) << 9) + swzh);
#pragma unroll
            for (int j = 0; j < 4; ++j)
                bfr[j] = *(const bf16x8*)(Blds + ((wc * 8 + j * 2 + kk) << 9) + swzh);
#pragma unroll
            for (int i = 0; i < 4; ++i)
#pragma unroll
                for (int j = 0; j < 4; ++j)
                    acc[i][j] = __builtin_amdgcn_mfma_f32_16x16x32_bf16(af[i], bfr[j], acc[i][j], 0, 0, 0);
        }
        __syncthreads();
    }
}

__global__ __launch_bounds__(256, 2) void gru_gemm(
    const u16* __restrict__ xbf, const u16* __restrict__ hbf,
    const u16* __restrict__ Wr, const u16* __restrict__ Ur,
    const u16* __restrict__ Wz, const u16* __restrict__ Uz,
    const u16* __restrict__ Wh, const u16* __restrict__ Uh,
    const float* __restrict__ Wr_b, const float* __restrict__ Ur_b,
    const float* __restrict__ Wz_b, const float* __restrict__ Uz_b,
    const float* __restrict__ Wh_b, const float* __restrict__ Uh_b,
    u16* __restrict__ z_out, u16* __restrict__ hpre_out, float* __restrict__ partials) {
    __shared__ __align__(16) u16 Alds[128 * 64];
    __shared__ __align__(16) u16 Blds[128 * 64];
    __shared__ float redS[4], redSS[4];

    const int tid = threadIdx.x;
    // XCD-aware bijective remap: 1024 blocks, 8 XCDs, 128 consecutive per XCD
    const int bid = blockIdx.x;
    const int wg = (bid & 7) * 128 + (bid >> 3);
    const int m0 = (wg & 31) * 128, n0 = (wg >> 5) * 128;
    const int l = tid & 63, wid = tid >> 6;
    const int wr = wid >> 1, wc = wid & 1;

    f32x4 acc[4][4];

    // ---- reset gate: r = sigmoid(Wr x + Ur h + br + bur) ----
    zero_acc(acc);
    run_phase(xbf, m0, Wr + (size_t)n0 * IND, IND, IND, Alds, Blds, acc, tid);
    run_phase(hbf, m0, Ur + (size_t)n0 * HH, HH, HH, Alds, Blds, acc, tid);

    float r_st[4][4][4];
#pragma unroll
    for (int j = 0; j < 4; ++j) {
        int col = n0 + wc * 64 + j * 16 + (l & 15);
        float bias = __ldg(Wr_b + col) + __ldg(Ur_b + col);
#pragma unroll
        for (int i = 0; i < 4; ++i)
#pragma unroll
            for (int q = 0; q < 4; ++q)
                r_st[i][j][q] = 1.f / (1.f + __expf(-(acc[i][j][q] + bias)));
    }

    // ---- update gate: z = sigmoid(Wz x + Uz h + bz + buz) -> write bf16 ----
    zero_acc(acc);
    run_phase(xbf, m0, Wz + (size_t)n0 * IND, IND, IND, Alds, Blds, acc, tid);
    run_phase(hbf, m0, Uz + (size_t)n0 * HH, HH, HH, Alds, Blds, acc, tid);
#pragma unroll
    for (int j = 0; j < 4; ++j) {
        int col = n0 + wc * 64 + j * 16 + (l & 15);
        float bias = __ldg(Wz_b + col) + __ldg(Uz_b + col);
#pragma unroll
        for (int i = 0; i < 4; ++i) {
            int rowb = m0 + wr * 64 + i * 16 + (l >> 4) * 4;
#pragma unroll
            for (int q = 0; q < 4; ++q) {
                float zv = 1.f / (1.f + __expf(-(acc[i][j][q] + bias)));
                z_out[(size_t)(rowb + q) * HH + col] = f2bf(zv);
            }
        }
    }

    // ---- h_pre = (Wh x + bwh) + r*(Uh h + buh) ----
    zero_acc(acc);
    run_phase(hbf, m0, Uh + (size_t)n0 * HH, HH, HH, Alds, Blds, acc, tid);
#pragma unroll
    for (int j = 0; j < 4; ++j) {
        int col = n0 + wc * 64 + j * 16 + (l & 15);
        float bias = __ldg(Uh_b + col);
#pragma unroll
        for (int i = 0; i < 4; ++i)
#pragma unroll
            for (int q = 0; q < 4; ++q)
                acc[i][j][q] = r_st[i][j][q] * (acc[i][j][q] + bias);
    }
    // accumulate Wh x on top (MFMA C-in is linear)
    run_phase(xbf, m0, Wh + (size_t)n0 * IND, IND, IND, Alds, Blds, acc, tid);

    float s = 0.f, ss = 0.f;
#pragma unroll
    for (int j = 0; j < 4; ++j) {
        int col = n0 + wc * 64 + j * 16 + (l & 15);
        float bias = __ldg(Wh_b + col);
#pragma unroll
        for (int i = 0; i < 4; ++i) {
            int rowb = m0 + wr * 64 + i * 16 + (l >> 4) * 4;
#pragma unroll
            for (int q = 0; q < 4; ++q) {
                float hv = acc[i][j][q] + bias;
                hpre_out[(size_t)(rowb + q) * HH + col] = f2bf(hv);
                s += hv;
                ss += hv * hv;
            }
        }
    }
    // deterministic block partials for global mean/var
#pragma unroll
    for (int off = 32; off; off >>= 1) {
        s += __shfl_down(s, off, 64);
        ss += __shfl_down(ss, off, 64);
    }
    if (l == 0) { redS[wid] = s; redSS[wid] = ss; }
    __syncthreads();
    if (tid == 0) {
        partials[2 * bid] = redS[0] + redS[1] + redS[2] + redS[3];
        partials[2 * bid + 1] = redSS[0] + redSS[1] + redSS[2] + redSS[3];
    }
}

// ---------------- stats reduce ----------------
__global__ void reduce_stats(const float* __restrict__ partials, int nblk,
                             const float* __restrict__ gamma, const float* __restrict__ beta,
                             float* __restrict__ stats) {
    __shared__ float rs[4], rss[4];
    int tid = threadIdx.x;
    float s = 0.f, ss = 0.f;
    for (int i = tid; i < nblk; i += blockDim.x) {
        s += partials[2 * i];
        ss += partials[2 * i + 1];
    }
#pragma unroll
    for (int off = 32; off; off >>= 1) {
        s += __shfl_down(s, off, 64);
        ss += __shfl_down(ss, off, 64);
    }
    if ((tid & 63) == 0) { rs[tid >> 6] = s; rss[tid >> 6] = ss; }
    __syncthreads();
    if (tid == 0) {
        float S = rs[0] + rs[1] + rs[2] + rs[3];
        float SS = rss[0] + rss[1] + rss[2] + rss[3];
        float mean = S / (float)NTOT;
        float var = SS / (float)NTOT - mean * mean;
        float scale = gamma[0] * rsqrtf(var + EPSV);
        stats[0] = scale;
        stats[1] = beta[0] - mean * scale;
    }
}

// ---------------- finalize: BN + blend + 4-way GEMV head ----------------
__global__ __launch_bounds__(256) void finalize(
    const u16* __restrict__ z, const u16* __restrict__ hpre,
    const float* __restrict__ hidden, const float* __restrict__ out_w,
    const float* __restrict__ out_b, const float* __restrict__ stats,
    float* __restrict__ d_out) {
    __shared__ float red[4][4];
    const int b = blockIdx.x, t = threadIdx.x;
    const float scale = stats[0], shift = stats[1];
    const size_t row = (size_t)b * HH;
    float so[4] = {0.f, 0.f, 0.f, 0.f};
#pragma unroll
    for (int jj = 0; jj < 2; ++jj) {
        int h0 = jj * 2048 + t * 8;
        u16x8 zv = *(const u16x8*)(z + row + h0);
        u16x8 hp = *(const u16x8*)(hpre + row + h0);
        f32x4 hd0 = *(const f32x4*)(hidden + row + h0);
        f32x4 hd1 = *(const f32x4*)(hidden + row + h0 + 4);
        f32x4 o0, o1;
#pragma unroll
        for (int e = 0; e < 8; ++e) {
            float zf = bf2f(zv[e]);
            float pv = bf2f(hp[e]) * scale + shift;
            pv = pv > 0.f ? pv : 0.f;
            float hf = (e < 4) ? hd0[e] : hd1[e - 4];
            float cs = (1.f - zf) * hf + zf * pv;
            if (e < 4) o0[e] = cs; else o1[e - 4] = cs;
#pragma unroll
            for (int o = 0; o < 4; ++o)
                so[o] += cs * __ldg(out_w + o * HH + h0 + e);
        }
        *(f32x4*)(d_out + row + h0) = o0;
        *(f32x4*)(d_out + row + h0 + 4) = o1;
    }
#pragma unroll
    for (int off = 32; off; off >>= 1)
#pragma unroll
        for (int o = 0; o < 4; ++o) so[o] += __shfl_down(so[o], off, 64);
    if ((t & 63) == 0)
#pragma unroll
        for (int o = 0; o < 4; ++o) red[t >> 6][o] = so[o];
    __syncthreads();
    if (t < 4) {
        float v = red[0][t] + red[1][t] + red[2][t] + red[3][t] + __ldg(out_b + t);
        d_out[(size_t)NTOT + (size_t)t * BB + b] = v;
    }
}

extern "C" void kernel_launch(void* const* d_in, const int* in_sizes, int n_in,
                              void* d_out, int out_size, void* d_ws, size_t ws_size,
                              hipStream_t stream) {
    const float* input = (const float*)d_in[0];
    const float* hidden = (const float*)d_in[3];
    const float* Wr_w = (const float*)d_in[4];  const float* Wr_b = (const float*)d_in[5];
    const float* Ur_w = (const float*)d_in[6];  const float* Ur_b = (const float*)d_in[7];
    const float* Wz_w = (const float*)d_in[8];  const float* Wz_b = (const float*)d_in[9];
    const float* Uz_w = (const float*)d_in[10]; const float* Uz_b = (const float*)d_in[11];
    const float* Wh_w = (const float*)d_in[12]; const float* Wh_b = (const float*)d_in[13];
    const float* Uh_w = (const float*)d_in[14]; const float* Uh_b = (const float*)d_in[15];
    const float* out_w = (const float*)d_in[16]; const float* out_b = (const float*)d_in[17];
    const float* gamma = (const float*)d_in[18]; const float* beta = (const float*)d_in[19];

    char* ws = (char*)d_ws;
    size_t off = 0;
    auto alloc = [&](size_t bytes) {
        void* p = ws + off;
        off = (off + bytes + 255) & ~(size_t)255;
        return p;
    };
    u16* xbf = (u16*)alloc((size_t)BB * IND * 2);
    u16* hbf = (u16*)alloc((size_t)BB * HH * 2);
    u16* wr = (u16*)alloc((size_t)HH * IND * 2);
    u16* wz = (u16*)alloc((size_t)HH * IND * 2);
    u16* wh = (u16*)alloc((size_t)HH * IND * 2);
    u16* ur = (u16*)alloc((size_t)HH * HH * 2);
    u16* uz = (u16*)alloc((size_t)HH * HH * 2);
    u16* uh = (u16*)alloc((size_t)HH * HH * 2);
    u16* zpl = (u16*)alloc((size_t)BB * HH * 2);
    u16* hpl = (u16*)alloc((size_t)BB * HH * 2);
    float* partials = (float*)alloc(2048 * sizeof(float));
    float* stats = (float*)alloc(16);

    cvt_kernel<<<512, 256, 0, stream>>>(input, xbf, BB * IND);
    cvt_kernel<<<2048, 256, 0, stream>>>(hidden, hbf, BB * HH);
    cvt_kernel<<<512, 256, 0, stream>>>(Wr_w, wr, HH * IND);
    cvt_kernel<<<512, 256, 0, stream>>>(Wz_w, wz, HH * IND);
    cvt_kernel<<<512, 256, 0, stream>>>(Wh_w, wh, HH * IND);
    cvt_kernel<<<2048, 256, 0, stream>>>(Ur_w, ur, HH * HH);
    cvt_kernel<<<2048, 256, 0, stream>>>(Uz_w, uz, HH * HH);
    cvt_kernel<<<2048, 256, 0, stream>>>(Uh_w, uh, HH * HH);

    gru_gemm<<<1024, 256, 0, stream>>>(xbf, hbf, wr, ur, wz, uz, wh, uh,
                                       Wr_b, Ur_b, Wz_b, Uz_b, Wh_b, Uh_b,
                                       zpl, hpl, partials);
    reduce_stats<<<1, 256, 0, stream>>>(partials, 1024, gamma, beta, stats);
    finalize<<<BB, 256, 0, stream>>>(zpl, hpl, hidden, out_w, out_b, stats, (float*)d_out);
}

// Round 4
// 754.655 us; speedup vs baseline: 1.1726x; 1.1726x over previous
//
#include <hip/hip_runtime.h>

#define HH 4096
#define BB 4096
#define IND 1024
#define NTOT 16777216   // 4096*4096
#define EPSV 1e-5f

typedef unsigned short u16;
typedef __bf16 bf16x8 __attribute__((ext_vector_type(8)));
typedef float f32x4 __attribute__((ext_vector_type(4)));
typedef u16 u16x8 __attribute__((ext_vector_type(8)));

__device__ __forceinline__ u16 f2bf(float f) {
    unsigned u = __builtin_bit_cast(unsigned, f);
    u += 0x7fffu + ((u >> 16) & 1u);
    return (u16)(u >> 16);
}
__device__ __forceinline__ float bf2f(u16 h) {
    return __builtin_bit_cast(float, ((unsigned)h) << 16);
}

// ---------------- f32 -> bf16 conversion ----------------
__global__ void cvt_kernel(const float* __restrict__ src, u16* __restrict__ dst, int n) {
    int i4 = (blockIdx.x * blockDim.x + threadIdx.x) * 4;
    int stride = gridDim.x * blockDim.x * 4;
    for (; i4 < n; i4 += stride) {
        f32x4 v = *(const f32x4*)(src + i4);
        u16 o0 = f2bf(v[0]), o1 = f2bf(v[1]), o2 = f2bf(v[2]), o3 = f2bf(v[3]);
        unsigned p0 = (unsigned)o0 | ((unsigned)o1 << 16);
        unsigned p1 = (unsigned)o2 | ((unsigned)o3 << 16);
        *(uint2*)(dst + i4) = make_uint2(p0, p1);
    }
}

// ---------------- fused GRU GEMM ----------------
// 128x128 tile, BK=64, 4 waves, st_16x32 swizzled LDS (0 bank conflicts, R3).
// R4: r-gate lives in GLOBAL scratch (not 64 registers) -> VGPR cap 128 via
// __launch_bounds__(256,4) -> target 4 blocks/CU (occupancy 23% -> ~50%).

__device__ __forceinline__ void stage_tile(const u16* __restrict__ g, int ld, int row0, int k0,
                                           u16* lds, int tid) {
    const int l = tid & 63, w = tid >> 6;
#pragma unroll
    for (int j = 0; j < 4; ++j) {
        const int sub = j * 4 + w;                  // 0..15, wave-uniform
        const int d = l << 4;                       // linear byte chunk in subtile
        const int lin = d ^ (((d >> 9) & 1) << 5);  // involution: source element
        const int r = ((sub >> 1) << 4) | (lin >> 6);
        const int c = ((sub & 1) << 5) | ((lin & 63) >> 1);
        const u16* ga = g + (size_t)(row0 + r) * ld + (k0 + c);
        __builtin_amdgcn_global_load_lds(
            (const __attribute__((address_space(1))) unsigned*)ga,
            (__attribute__((address_space(3))) unsigned*)(lds + (sub << 9)),
            16, 0, 0);
    }
}

__device__ __forceinline__ void zero_acc(f32x4 (&acc)[4][4]) {
#pragma unroll
    for (int i = 0; i < 4; ++i)
#pragma unroll
        for (int j = 0; j < 4; ++j) {
            f32x4 zz = {0.f, 0.f, 0.f, 0.f};
            acc[i][j] = zz;
        }
}

__device__ __forceinline__ void run_phase(const u16* __restrict__ A, int row0a,
                                          const u16* __restrict__ B, int ld, int Klen,
                                          u16* Alds, u16* Blds,
                                          f32x4 (&acc)[4][4], int tid) {
    const int l = tid & 63;
    const int wid = tid >> 6;
    const int wr = wid >> 1, wc = wid & 1;
    const int lr = l & 15, lq = l >> 4;
    // lane-invariant swizzled offset within a subtile (u16 units)
    const int swzh = (((lr << 6) | (lq << 4)) ^ ((lr & 8) << 2)) >> 1;
    for (int k0 = 0; k0 < Klen; k0 += 64) {
        stage_tile(A, ld, row0a, k0, Alds, tid);
        stage_tile(B, ld, 0, k0, Blds, tid);
        __syncthreads();
#pragma unroll
        for (int kk = 0; kk < 2; ++kk) {
            bf16x8 af[4], bfr[4];
#pragma unroll
            for (int i = 0; i < 4; ++i)
                af[i] = *(const bf16x8*)(Alds + ((wr * 8 + i * 2 + kk) << 9) + swzh);
#pragma unroll
            for (int j = 0; j < 4; ++j)
                bfr[j] = *(const bf16x8*)(Blds + ((wc * 8 + j * 2 + kk) << 9) + swzh);
#pragma unroll
            for (int i = 0; i < 4; ++i)
#pragma unroll
                for (int j = 0; j < 4; ++j)
                    acc[i][j] = __builtin_amdgcn_mfma_f32_16x16x32_bf16(af[i], bfr[j], acc[i][j], 0, 0, 0);
        }
        __syncthreads();
    }
}

__global__ __launch_bounds__(256, 4) void gru_gemm(
    const u16* __restrict__ xbf, const u16* __restrict__ hbf,
    const u16* __restrict__ Wr, const u16* __restrict__ Ur,
    const u16* __restrict__ Wz, const u16* __restrict__ Uz,
    const u16* __restrict__ Wh, const u16* __restrict__ Uh,
    const float* __restrict__ Wr_b, const float* __restrict__ Ur_b,
    const float* __restrict__ Wz_b, const float* __restrict__ Uz_b,
    const float* __restrict__ Wh_b, const float* __restrict__ Uh_b,
    u16* __restrict__ r_out, u16* __restrict__ z_out,
    u16* __restrict__ hpre_out, float* __restrict__ partials) {
    __shared__ __align__(16) u16 Alds[128 * 64];
    __shared__ __align__(16) u16 Blds[128 * 64];
    __shared__ float redS[4], redSS[4];

    const int tid = threadIdx.x;
    const int m0 = blockIdx.x * 128, n0 = blockIdx.y * 128;
    const int l = tid & 63, wid = tid >> 6;
    const int wr = wid >> 1, wc = wid & 1;
    const int lr = l & 15, lq = l >> 4;

    f32x4 acc[4][4];

    // ---- reset gate: r = sigmoid(Wr x + Ur h + br + bur) -> GLOBAL scratch ----
    zero_acc(acc);
    run_phase(xbf, m0, Wr + (size_t)n0 * IND, IND, IND, Alds, Blds, acc, tid);
    run_phase(hbf, m0, Ur + (size_t)n0 * HH, HH, HH, Alds, Blds, acc, tid);
#pragma unroll
    for (int j = 0; j < 4; ++j) {
        int col = n0 + wc * 64 + j * 16 + lr;
        float bias = Wr_b[col] + Ur_b[col];
#pragma unroll
        for (int i = 0; i < 4; ++i) {
            int rowb = m0 + wr * 64 + i * 16 + lq * 4;
#pragma unroll
            for (int q = 0; q < 4; ++q) {
                float rv = 1.f / (1.f + __expf(-(acc[i][j][q] + bias)));
                r_out[(size_t)(rowb + q) * HH + col] = f2bf(rv);
            }
        }
    }

    // ---- update gate: z = sigmoid(Wz x + Uz h + bz + buz) ----
    zero_acc(acc);
    run_phase(xbf, m0, Wz + (size_t)n0 * IND, IND, IND, Alds, Blds, acc, tid);
    run_phase(hbf, m0, Uz + (size_t)n0 * HH, HH, HH, Alds, Blds, acc, tid);
#pragma unroll
    for (int j = 0; j < 4; ++j) {
        int col = n0 + wc * 64 + j * 16 + lr;
        float bias = Wz_b[col] + Uz_b[col];
#pragma unroll
        for (int i = 0; i < 4; ++i) {
            int rowb = m0 + wr * 64 + i * 16 + lq * 4;
#pragma unroll
            for (int q = 0; q < 4; ++q) {
                float zv = 1.f / (1.f + __expf(-(acc[i][j][q] + bias)));
                z_out[(size_t)(rowb + q) * HH + col] = f2bf(zv);
            }
        }
    }

    // ---- h_pre = (Wh x + bwh) + r*(Uh h + buh) ----
    zero_acc(acc);
    run_phase(hbf, m0, Uh + (size_t)n0 * HH, HH, HH, Alds, Blds, acc, tid);
#pragma unroll
    for (int j = 0; j < 4; ++j) {
        int col = n0 + wc * 64 + j * 16 + lr;
        float bias = Uh_b[col];
#pragma unroll
        for (int i = 0; i < 4; ++i) {
            int rowb = m0 + wr * 64 + i * 16 + lq * 4;
#pragma unroll
            for (int q = 0; q < 4; ++q) {
                float rv = bf2f(r_out[(size_t)(rowb + q) * HH + col]);
                acc[i][j][q] = rv * (acc[i][j][q] + bias);
            }
        }
    }
    // accumulate Wh x on top (MFMA C-in is linear)
    run_phase(xbf, m0, Wh + (size_t)n0 * IND, IND, IND, Alds, Blds, acc, tid);

    float s = 0.f, ss = 0.f;
#pragma unroll
    for (int j = 0; j < 4; ++j) {
        int col = n0 + wc * 64 + j * 16 + lr;
        float bias = Wh_b[col];
#pragma unroll
        for (int i = 0; i < 4; ++i) {
            int rowb = m0 + wr * 64 + i * 16 + lq * 4;
#pragma unroll
            for (int q = 0; q < 4; ++q) {
                float hv = acc[i][j][q] + bias;
                hpre_out[(size_t)(rowb + q) * HH + col] = f2bf(hv);
                s += hv;
                ss += hv * hv;
            }
        }
    }
    // deterministic block partials for global mean/var
#pragma unroll
    for (int off = 32; off; off >>= 1) {
        s += __shfl_down(s, off, 64);
        ss += __shfl_down(ss, off, 64);
    }
    if (l == 0) { redS[wid] = s; redSS[wid] = ss; }
    __syncthreads();
    if (tid == 0) {
        int bid = blockIdx.y * 32 + blockIdx.x;
        partials[2 * bid] = redS[0] + redS[1] + redS[2] + redS[3];
        partials[2 * bid + 1] = redSS[0] + redSS[1] + redSS[2] + redSS[3];
    }
}

// ---------------- stats reduce ----------------
__global__ void reduce_stats(const float* __restrict__ partials, int nblk,
                             const float* __restrict__ gamma, const float* __restrict__ beta,
                             float* __restrict__ stats) {
    __shared__ float rs[4], rss[4];
    int tid = threadIdx.x;
    float s = 0.f, ss = 0.f;
    for (int i = tid; i < nblk; i += blockDim.x) {
        s += partials[2 * i];
        ss += partials[2 * i + 1];
    }
#pragma unroll
    for (int off = 32; off; off >>= 1) {
        s += __shfl_down(s, off, 64);
        ss += __shfl_down(ss, off, 64);
    }
    if ((tid & 63) == 0) { rs[tid >> 6] = s; rss[tid >> 6] = ss; }
    __syncthreads();
    if (tid == 0) {
        float S = rs[0] + rs[1] + rs[2] + rs[3];
        float SS = rss[0] + rss[1] + rss[2] + rss[3];
        float mean = S / (float)NTOT;
        float var = SS / (float)NTOT - mean * mean;
        float scale = gamma[0] * rsqrtf(var + EPSV);
        stats[0] = scale;
        stats[1] = beta[0] - mean * scale;
    }
}

// ---------------- finalize: BN + blend + 4-way GEMV head ----------------
__global__ __launch_bounds__(256) void finalize(
    const u16* __restrict__ z, const u16* __restrict__ hpre,
    const float* __restrict__ hidden, const float* __restrict__ out_w,
    const float* __restrict__ out_b, const float* __restrict__ stats,
    float* __restrict__ d_out) {
    __shared__ float red[4][4];
    const int b = blockIdx.x, t = threadIdx.x;
    const float scale = stats[0], shift = stats[1];
    const size_t row = (size_t)b * HH;
    float so[4] = {0.f, 0.f, 0.f, 0.f};
#pragma unroll
    for (int jj = 0; jj < 2; ++jj) {
        int h0 = jj * 2048 + t * 8;
        u16x8 zv = *(const u16x8*)(z + row + h0);
        u16x8 hp = *(const u16x8*)(hpre + row + h0);
        f32x4 hd0 = *(const f32x4*)(hidden + row + h0);
        f32x4 hd1 = *(const f32x4*)(hidden + row + h0 + 4);
        f32x4 o0, o1;
#pragma unroll
        for (int e = 0; e < 8; ++e) {
            float zf = bf2f(zv[e]);
            float pv = bf2f(hp[e]) * scale + shift;
            pv = pv > 0.f ? pv : 0.f;
            float hf = (e < 4) ? hd0[e] : hd1[e - 4];
            float cs = (1.f - zf) * hf + zf * pv;
            if (e < 4) o0[e] = cs; else o1[e - 4] = cs;
#pragma unroll
            for (int o = 0; o < 4; ++o)
                so[o] += cs * __ldg(out_w + o * HH + h0 + e);
        }
        *(f32x4*)(d_out + row + h0) = o0;
        *(f32x4*)(d_out + row + h0 + 4) = o1;
    }
#pragma unroll
    for (int off = 32; off; off >>= 1)
#pragma unroll
        for (int o = 0; o < 4; ++o) so[o] += __shfl_down(so[o], off, 64);
    if ((t & 63) == 0)
#pragma unroll
        for (int o = 0; o < 4; ++o) red[t >> 6][o] = so[o];
    __syncthreads();
    if (t < 4) {
        float v = red[0][t] + red[1][t] + red[2][t] + red[3][t] + __ldg(out_b + t);
        d_out[(size_t)NTOT + (size_t)t * BB + b] = v;
    }
}

extern "C" void kernel_launch(void* const* d_in, const int* in_sizes, int n_in,
                              void* d_out, int out_size, void* d_ws, size_t ws_size,
                              hipStream_t stream) {
    const float* input = (const float*)d_in[0];
    const float* hidden = (const float*)d_in[3];
    const float* Wr_w = (const float*)d_in[4];  const float* Wr_b = (const float*)d_in[5];
    const float* Ur_w = (const float*)d_in[6];  const float* Ur_b = (const float*)d_in[7];
    const float* Wz_w = (const float*)d_in[8];  const float* Wz_b = (const float*)d_in[9];
    const float* Uz_w = (const float*)d_in[10]; const float* Uz_b = (const float*)d_in[11];
    const float* Wh_w = (const float*)d_in[12]; const float* Wh_b = (const float*)d_in[13];
    const float* Uh_w = (const float*)d_in[14]; const float* Uh_b = (const float*)d_in[15];
    const float* out_w = (const float*)d_in[16]; const float* out_b = (const float*)d_in[17];
    const float* gamma = (const float*)d_in[18]; const float* beta = (const float*)d_in[19];

    char* ws = (char*)d_ws;
    size_t off = 0;
    auto alloc = [&](size_t bytes) {
        void* p = ws + off;
        off = (off + bytes + 255) & ~(size_t)255;
        return p;
    };
    u16* xbf = (u16*)alloc((size_t)BB * IND * 2);
    u16* hbf = (u16*)alloc((size_t)BB * HH * 2);
    u16* wr = (u16*)alloc((size_t)HH * IND * 2);
    u16* wz = (u16*)alloc((size_t)HH * IND * 2);
    u16* wh = (u16*)alloc((size_t)HH * IND * 2);
    u16* ur = (u16*)alloc((size_t)HH * HH * 2);
    u16* uz = (u16*)alloc((size_t)HH * HH * 2);
    u16* uh = (u16*)alloc((size_t)HH * HH * 2);
    u16* zpl = (u16*)alloc((size_t)BB * HH * 2);
    u16* hpl = (u16*)alloc((size_t)BB * HH * 2);
    float* partials = (float*)alloc(2048 * sizeof(float));
    float* stats = (float*)alloc(16);

    // r-plane scratch in d_out's first 32MB (consumed before finalize
    // overwrites all of d_out) -- proven safe in R2.
    u16* rpl = (u16*)d_out;

    cvt_kernel<<<512, 256, 0, stream>>>(input, xbf, BB * IND);
    cvt_kernel<<<2048, 256, 0, stream>>>(hidden, hbf, BB * HH);
    cvt_kernel<<<512, 256, 0, stream>>>(Wr_w, wr, HH * IND);
    cvt_kernel<<<512, 256, 0, stream>>>(Wz_w, wz, HH * IND);
    cvt_kernel<<<512, 256, 0, stream>>>(Wh_w, wh, HH * IND);
    cvt_kernel<<<2048, 256, 0, stream>>>(Ur_w, ur, HH * HH);
    cvt_kernel<<<2048, 256, 0, stream>>>(Uz_w, uz, HH * HH);
    cvt_kernel<<<2048, 256, 0, stream>>>(Uh_w, uh, HH * HH);

    gru_gemm<<<dim3(32, 32), 256, 0, stream>>>(xbf, hbf, wr, ur, wz, uz, wh, uh,
                                               Wr_b, Ur_b, Wz_b, Uz_b, Wh_b, Uh_b,
                                               rpl, zpl, hpl, partials);
    reduce_stats<<<1, 256, 0, stream>>>(partials, 1024, gamma, beta, stats);
    finalize<<<BB, 256, 0, stream>>>(zpl, hpl, hidden, out_w, out_b, stats, (float*)d_out);
}